// Round 13
// baseline (516.424 us; speedup 1.0000x reference)
//
#include <hip/hip_runtime.h>

#define HDIM 128
#define NGRAPH 64
#define NCLASS 7
#define PG_NODES 192  // nodes per k_pgemm block (3 sub-chunks of 64)

// ---------------- count in-degree (+edge rank, 4 strided edges/thread) ----------------

__global__ void k_countw(const int* __restrict__ col, int E, int* __restrict__ deg,
                         int* __restrict__ rank, int cB) {
  int tid = blockIdx.x * 256 + threadIdx.x;
  int stride = cB << 8;
#pragma unroll
  for (int k = 0; k < 4; k++) {
    int e = tid + k * stride;
    if (e < E) rank[e] = atomicAdd(&deg[col[e]], 1);
  }
}

// exclusive scan of deg (tile-local) -> packed node metadata + self-term inits:
//   od[i] = { off_local | batch[i]<<24 , dinv_bits }
//   dx[i] = { dinv , x }                         (k_edge r-side)
//   sd[i] = { dinv^2 * x  (s self-init) , dinv } (k_l2in src-side; s accumulated into .x)
//   P[i][batch[i]] = dinv^2                      (self pooling coef; P pre-zeroed, Path A)
__global__ void k_scan1(const int* __restrict__ in, int n, const int* __restrict__ batch,
                        const float* __restrict__ x, int2* __restrict__ od,
                        float2* __restrict__ dx, float2* __restrict__ sd,
                        float* __restrict__ P, int* __restrict__ tileSums) {
  __shared__ int sh[256];
  int t = threadIdx.x;
  int base = blockIdx.x * 1024 + t * 4;
  int v[4], dg[4], sum = 0;
#pragma unroll
  for (int j = 0; j < 4; j++) {
    int idx = base + j;
    int d = (idx < n) ? in[idx] : 0;
    dg[j] = d;
    v[j] = sum; sum += d;
  }
  sh[t] = sum; __syncthreads();
  for (int o = 1; o < 256; o <<= 1) {
    int val = (t >= o) ? sh[t - o] : 0;
    __syncthreads();
    sh[t] += val;
    __syncthreads();
  }
  int excl = (t == 0) ? 0 : sh[t - 1];
  if (t == 255) tileSums[blockIdx.x] = sh[255];
#pragma unroll
  for (int j = 0; j < 4; j++) {
    int idx = base + j;
    if (idx < n) {
      int g = batch[idx];
      float xv = x[idx];
      float dinv = rsqrtf((float)(dg[j] + 1));  // +1 self-loop
      float dd = dinv * dinv;
      od[idx] = make_int2((excl + v[j]) | (g << 24), __float_as_int(dinv));
      dx[idx] = make_float2(dinv, xv);
      sd[idx] = make_float2(dd * xv, dinv);
      if (P) P[(size_t)idx * NGRAPH + g] = dd;
    }
  }
}

__global__ void k_scan2(int* __restrict__ tileSums, int numTiles) {
  __shared__ int sh[128];
  int t = threadIdx.x;
  sh[t] = (t < numTiles) ? tileSums[t] : 0;
  __syncthreads();
  for (int o = 1; o < 128; o <<= 1) {
    int val = (t >= o) ? sh[t - o] : 0;
    __syncthreads();
    sh[t] += val;
    __syncthreads();
  }
  if (t < numTiles) tileSums[t] = (t == 0) ? 0 : sh[t - 1];
}

// ---------------- edge pass: CSR fill (4B payload) + layer-1 agg + P accumulation ----------------

__global__ void k_edge(const int* __restrict__ row, const int* __restrict__ col,
                       const int* __restrict__ rank, int E,
                       const int2* __restrict__ od, const int* __restrict__ ts,
                       const float2* __restrict__ dx,
                       float2* __restrict__ sd, int* __restrict__ gwi,
                       float* __restrict__ P) {
  int e = blockIdx.x * blockDim.x + threadIdx.x;
  if (e >= E) return;
  int r = row[e], c = col[e];
  int2 oc = od[c];
  float2 dr = dx[r];
  float w = dr.x * __int_as_float(oc.y);
  int g = ((unsigned)oc.x) >> 24;
  int pos = (oc.x & 0xFFFFFF) + ts[c >> 10] + rank[e];
  gwi[pos] = r | (g << 20);
  unsafeAtomicAdd(&sd[c].x, w * dr.y);
  if (P) unsafeAtomicAdd(&P[(size_t)r * NGRAPH + g], w);
}

// ---------------- P build fallback (Path B only) ----------------

__global__ void k_pbuild(const int* __restrict__ row, const int* __restrict__ col, int E,
                         const int2* __restrict__ od, const float2* __restrict__ dx,
                         float* __restrict__ P, int n) {
  int e = blockIdx.x * blockDim.x + threadIdx.x;
  if (e < E) {
    int r = row[e], c = col[e];
    int2 oc = od[c];
    float w = dx[r].x * __int_as_float(oc.y);
    unsafeAtomicAdd(&P[(size_t)r * NGRAPH + (((unsigned)oc.x) >> 24)], w);
  } else if (e - E < n) {
    int i = e - E;
    float d = dx[i].x;
    int g = ((unsigned)od[i].x) >> 24;
    unsafeAtomicAdd(&P[(size_t)i * NGRAPH + g], d * d);
  }
}

// ---------------- fused: h1 = relu(s*W1+b1) recomputed per edge + agg2 ----------------

__global__ void __launch_bounds__(256) k_l2in(const float2* __restrict__ sd,
                                              const int2* __restrict__ od,
                                              const int* __restrict__ ts,
                                              const int* __restrict__ gwi,
                                              const float* __restrict__ W1,
                                              const float* __restrict__ b1,
                                              float2* __restrict__ z, int n, int E) {
  int node = blockIdx.x * 4 + (threadIdx.x >> 6);
  if (node >= n) return;
  int l = threadIdx.x & 63;
  float2 w1 = ((const float2*)W1)[l];
  float2 bv = ((const float2*)b1)[l];
  int2 on = od[node];
  float dstd = __int_as_float(on.y);
  float nself = dstd * dstd;
  float sv = sd[node].x;
  float2 acc;
  acc.x = nself * fmaxf(fmaf(sv, w1.x, bv.x), 0.f);
  acc.y = nself * fmaxf(fmaf(sv, w1.y, bv.y), 0.f);
  int e0 = (on.x & 0xFFFFFF) + ts[node >> 10];
  int e1 = (node + 1 < n) ? ((od[node + 1].x & 0xFFFFFF) + ts[(node + 1) >> 10]) : E;
  int e = e0;
  for (; e + 4 <= e1; e += 4) {
    int g0 = gwi[e], g1 = gwi[e + 1], g2 = gwi[e + 2], g3 = gwi[e + 3];
    float2 q0 = sd[g0 & 0xFFFFF], q1 = sd[g1 & 0xFFFFF];
    float2 q2 = sd[g2 & 0xFFFFF], q3 = sd[g3 & 0xFFFFF];
    float u0 = q0.y * dstd, u1 = q1.y * dstd, u2 = q2.y * dstd, u3 = q3.y * dstd;
    acc.x = fmaf(u0, fmaxf(fmaf(q0.x, w1.x, bv.x), 0.f), acc.x);
    acc.y = fmaf(u0, fmaxf(fmaf(q0.x, w1.y, bv.y), 0.f), acc.y);
    acc.x = fmaf(u1, fmaxf(fmaf(q1.x, w1.x, bv.x), 0.f), acc.x);
    acc.y = fmaf(u1, fmaxf(fmaf(q1.x, w1.y, bv.y), 0.f), acc.y);
    acc.x = fmaf(u2, fmaxf(fmaf(q2.x, w1.x, bv.x), 0.f), acc.x);
    acc.y = fmaf(u2, fmaxf(fmaf(q2.x, w1.y, bv.y), 0.f), acc.y);
    acc.x = fmaf(u3, fmaxf(fmaf(q3.x, w1.x, bv.x), 0.f), acc.x);
    acc.y = fmaf(u3, fmaxf(fmaf(q3.x, w1.y, bv.y), 0.f), acc.y);
  }
  for (; e < e1; e++) {
    int gg = gwi[e];
    float2 q = sd[gg & 0xFFFFF];
    float w = q.y * dstd;
    acc.x = fmaf(w, fmaxf(fmaf(q.x, w1.x, bv.x), 0.f), acc.x);
    acc.y = fmaf(w, fmaxf(fmaf(q.x, w1.y, bv.y), 0.f), acc.y);
  }
  z[(size_t)node * 64 + l] = acc;
}

// ---------------- GEMM v2: broadcast-A, no LDS, no barriers ----------------
// Lane l owns cols {2l, 2l+1}; wave owns 32 rows. A[r][k] is lane-uniform ->
// b128 broadcast load (single transaction). W[k][2l] is a coalesced float2
// load straight from L2/L3 (W2 row-major used directly; no transpose).
// Per k-quad per wave: 32 broadcast A loads + 4 W loads + 256 fma. Zero LDS,
// zero __syncthreads -> no barrier drains (the 76us kernel's stall source).
// Same k-order summation as before (numerically identical).

__global__ void __launch_bounds__(256)
k_gemm2(const float* __restrict__ A, const float* __restrict__ W,
        const float* __restrict__ bias, float* __restrict__ out, int n) {
  const int l = threadIdx.x & 63;
  const int wv = threadIdx.x >> 6;
  const int row0 = (blockIdx.x << 7) + (wv << 5);
  const float2* __restrict__ Wv = (const float2*)W;

  float2 acc[32];
#pragma unroll
  for (int r = 0; r < 32; r++) acc[r] = make_float2(0.f, 0.f);

  const float* __restrict__ a0 = A + (size_t)row0 * 128;

  if (row0 + 32 <= n) {
    // clean path: whole strip in range
    for (int k0 = 0; k0 < 128; k0 += 4) {
      float2 w0 = Wv[(k0 + 0) * 64 + l];
      float2 w1 = Wv[(k0 + 1) * 64 + l];
      float2 w2 = Wv[(k0 + 2) * 64 + l];
      float2 w3 = Wv[(k0 + 3) * 64 + l];
#pragma unroll
      for (int r = 0; r < 32; r++) {
        float4 a = *(const float4*)&a0[r * 128 + k0];
        acc[r].x = fmaf(a.x, w0.x, acc[r].x);
        acc[r].y = fmaf(a.x, w0.y, acc[r].y);
        acc[r].x = fmaf(a.y, w1.x, acc[r].x);
        acc[r].y = fmaf(a.y, w1.y, acc[r].y);
        acc[r].x = fmaf(a.z, w2.x, acc[r].x);
        acc[r].y = fmaf(a.z, w2.y, acc[r].y);
        acc[r].x = fmaf(a.w, w3.x, acc[r].x);
        acc[r].y = fmaf(a.w, w3.y, acc[r].y);
      }
    }
  } else if (row0 < n) {
    // tail strip: per-row guard on loads
    for (int k0 = 0; k0 < 128; k0 += 4) {
      float2 w0 = Wv[(k0 + 0) * 64 + l];
      float2 w1 = Wv[(k0 + 1) * 64 + l];
      float2 w2 = Wv[(k0 + 2) * 64 + l];
      float2 w3 = Wv[(k0 + 3) * 64 + l];
#pragma unroll
      for (int r = 0; r < 32; r++) {
        if (row0 + r < n) {
          float4 a = *(const float4*)&a0[r * 128 + k0];
          acc[r].x = fmaf(a.x, w0.x, acc[r].x);
          acc[r].y = fmaf(a.x, w0.y, acc[r].y);
          acc[r].x = fmaf(a.y, w1.x, acc[r].x);
          acc[r].y = fmaf(a.y, w1.y, acc[r].y);
          acc[r].x = fmaf(a.z, w2.x, acc[r].x);
          acc[r].y = fmaf(a.z, w2.y, acc[r].y);
          acc[r].x = fmaf(a.w, w3.x, acc[r].x);
          acc[r].y = fmaf(a.w, w3.y, acc[r].y);
        }
      }
    }
  } else {
    return;
  }

  float2 bv = ((const float2*)bias)[l];
#pragma unroll
  for (int r = 0; r < 32; r++) {
    int row = row0 + r;
    if (row < n) {
      float2 o;
      o.x = fmaxf(acc[r].x + bv.x, 0.f);
      o.y = fmaxf(acc[r].y + bv.y, 0.f);
      *(float2*)&out[(size_t)row * 128 + (l << 1)] = o;
    }
  }
}

// ---------------- layer 3 + pool: partials[b] = P_b^T * H_b ----------------

__global__ void __launch_bounds__(256) k_pgemm(const float* __restrict__ H,
                                               const float* __restrict__ P,
                                               float* __restrict__ partials, int n) {
  __shared__ float4 Hl4[64 * 32];  // [i][j-quad]
  __shared__ float4 Pl4[64 * 16];  // [i][g-quad]
  const int t = threadIdx.x;
  const int jl = t & 31;
  const int gq = (t >> 5) << 1;
  float4 acc[8];
#pragma unroll
  for (int i = 0; i < 8; i++) acc[i] = make_float4(0.f, 0.f, 0.f, 0.f);
  const int base0 = blockIdx.x * PG_NODES;

  for (int sub = 0; sub < PG_NODES / 64; sub++) {
    const int base = base0 + sub * 64;
    __syncthreads();
    for (int l = t; l < 2048; l += 256) {
      int i = l >> 5, q = l & 31;
      int node = base + i;
      Hl4[l] = (node < n) ? *(const float4*)&H[(size_t)node * 128 + (q << 2)]
                          : make_float4(0.f, 0.f, 0.f, 0.f);
    }
    for (int l = t; l < 1024; l += 256) {
      int i = l >> 4, q = l & 15;
      int node = base + i;
      Pl4[l] = (node < n) ? *(const float4*)&P[(size_t)node * NGRAPH + (q << 2)]
                          : make_float4(0.f, 0.f, 0.f, 0.f);
    }
    __syncthreads();

#define FMA4(A, PV) \
  A.x = fmaf(PV, hv.x, A.x); A.y = fmaf(PV, hv.y, A.y); \
  A.z = fmaf(PV, hv.z, A.z); A.w = fmaf(PV, hv.w, A.w);
#pragma unroll 4
    for (int i = 0; i < 64; i++) {
      float4 hv = Hl4[i * 32 + jl];
      float4 pa = Pl4[i * 16 + gq];
      float4 pb = Pl4[i * 16 + gq + 1];
      FMA4(acc[0], pa.x) FMA4(acc[1], pa.y) FMA4(acc[2], pa.z) FMA4(acc[3], pa.w)
      FMA4(acc[4], pb.x) FMA4(acc[5], pb.y) FMA4(acc[6], pb.z) FMA4(acc[7], pb.w)
    }
#undef FMA4
  }

  float* dst = &partials[(size_t)blockIdx.x * (NGRAPH * HDIM)];
  int gb = (t >> 5) << 3;
#pragma unroll
  for (int gi = 0; gi < 8; gi++)
    *(float4*)&dst[(gb + gi) * HDIM + (jl << 2)] = acc[gi];
}

// parallel partials reduce: grid (32, 8), block 256
__global__ void k_reduce(const float* __restrict__ partials, float* __restrict__ pooled,
                         int nparts) {
  int cell = blockIdx.x * 256 + threadIdx.x;
  int stride = gridDim.y;
  int p = blockIdx.y;
  float a0 = 0.f, a1 = 0.f, a2 = 0.f, a3 = 0.f;
  for (; p + 3 * stride < nparts; p += 4 * stride) {
    a0 += partials[(size_t)p * 8192 + cell];
    a1 += partials[(size_t)(p + stride) * 8192 + cell];
    a2 += partials[(size_t)(p + 2 * stride) * 8192 + cell];
    a3 += partials[(size_t)(p + 3 * stride) * 8192 + cell];
  }
  for (; p < nparts; p += stride) a0 += partials[(size_t)p * 8192 + cell];
  unsafeAtomicAdd(&pooled[cell], (a0 + a1) + (a2 + a3));
}

// fused tail: t1 = pooled/cnt @ W3 + b3 (in LDS), then out = t1 @ Wl + bl
__global__ void k_mid(const float* __restrict__ pooled, const int* __restrict__ batch, int n,
                      const float* __restrict__ W3, const float* __restrict__ b3,
                      const float* __restrict__ Wl, const float* __restrict__ bl,
                      float* __restrict__ out) {
  __shared__ float sh[HDIM];
  __shared__ float invSh;
  int g = blockIdx.x, j = threadIdx.x;
  if (j == 0) {
    int lo = 0, hi = n;
    while (lo < hi) { int m = (lo + hi) >> 1; if (batch[m] < g) lo = m + 1; else hi = m; }
    int a = lo;
    lo = 0; hi = n;
    while (lo < hi) { int m = (lo + hi) >> 1; if (batch[m] < g + 1) lo = m + 1; else hi = m; }
    invSh = 1.f / fmaxf((float)(lo - a), 1.f);
  }
  __syncthreads();
  float inv = invSh;
  float acc = 0.f;
  for (int k = 0; k < HDIM; k++) acc = fmaf(pooled[g * HDIM + k], W3[k * HDIM + j], acc);
  sh[j] = acc * inv + b3[j];
  __syncthreads();
  if (j < NCLASS) {
    float o = bl[j];
    for (int k = 0; k < HDIM; k++) o = fmaf(sh[k], Wl[k * NCLASS + j], o);
    out[g * NCLASS + j] = o;
  }
}

// ---------------- host ----------------

extern "C" void kernel_launch(void* const* d_in, const int* in_sizes, int n_in,
                              void* d_out, int out_size, void* d_ws, size_t ws_size,
                              hipStream_t stream) {
  const float* x   = (const float*)d_in[0];
  const int*   ei  = (const int*)d_in[1];
  const int*   bat = (const int*)d_in[2];
  const float* W1  = (const float*)d_in[3];
  const float* b1  = (const float*)d_in[4];
  const float* W2  = (const float*)d_in[5];
  const float* b2  = (const float*)d_in[6];
  const float* W3  = (const float*)d_in[7];
  const float* b3  = (const float*)d_in[8];
  const float* Wl  = (const float*)d_in[9];
  const float* bl  = (const float*)d_in[10];
  float* out = (float*)d_out;

  const int n = in_sizes[0];
  const int E = in_sizes[1] / 2;
  const int* rowv = ei;            // edge_index[0] : message source
  const int* colv = ei + E;        // edge_index[1] : aggregation destination

  char* w = (char*)d_ws;
  size_t o = 0;
  auto alloc = [&](size_t bytes) {
    size_t r = (o + 255) & ~(size_t)255;
    o = r + bytes;
    return r;
  };
  const int nPB = (n + PG_NODES - 1) / PG_NODES;

  // Path A layout: standalone P + partials; single upfront memset (deg, pooled, P).
  size_t o_deg  = alloc((size_t)n * 4);
  size_t o_pool = alloc((size_t)NGRAPH * HDIM * 4);
  size_t o_P    = alloc((size_t)n * NGRAPH * 4);  // 25.6 MB
  size_t zero_end = o;
  size_t o_ts   = alloc(256 * 4);
  size_t o_od   = alloc((size_t)n * 8);
  size_t o_dx   = alloc((size_t)n * 8);
  size_t o_sd   = alloc((size_t)n * 8);
  size_t o_rank = alloc((size_t)E * 4);
  size_t o_gw   = alloc((size_t)E * 4);
  size_t o_bufA = alloc((size_t)n * HDIM * 4);
  size_t o_bufB = alloc((size_t)n * HDIM * 4);
  size_t o_part = alloc((size_t)nPB * NGRAPH * HDIM * 4);  // ~17 MB
  const bool fitsA = (o <= ws_size);
  (void)n_in; (void)out_size;

  if (!fitsA) {
    // Path B: P + partials alias bufB (z dead after gemm); P built by k_pbuild.
    o = 0;
    o_deg  = alloc((size_t)n * 4);
    o_pool = alloc((size_t)NGRAPH * HDIM * 4);
    zero_end = o;
    o_ts   = alloc(256 * 4);
    o_od   = alloc((size_t)n * 8);
    o_dx   = alloc((size_t)n * 8);
    o_sd   = alloc((size_t)n * 8);
    o_rank = alloc((size_t)E * 4);
    o_gw   = alloc((size_t)E * 4);
    o_bufA = alloc((size_t)n * HDIM * 4);
    o_bufB = alloc((size_t)n * HDIM * 4);
    o_P    = o_bufB;
    o_part = o_bufB + (size_t)n * NGRAPH * 4;
  }

  int*    deg      = (int*)(w + o_deg);
  float*  pooled   = (float*)(w + o_pool);
  int*    ts       = (int*)(w + o_ts);
  int2*   od       = (int2*)(w + o_od);
  float2* dx       = (float2*)(w + o_dx);
  float2* sd       = (float2*)(w + o_sd);
  int*    rank     = (int*)(w + o_rank);
  int*    gwi      = (int*)(w + o_gw);
  float*  bufA     = (float*)(w + o_bufA);   // h2 (gemm out)
  float*  bufB     = (float*)(w + o_bufB);   // z (gemm in)
  float*  P        = (float*)(w + o_P);
  float*  partials = (float*)(w + o_part);

  hipMemsetAsync(w + o_deg, 0, zero_end - o_deg, stream);

  const int nTiles = (n + 1023) / 1024;
  const int cB = (E + 1023) / 1024;  // 4 strided edges per thread
  k_countw<<<cB, 256, 0, stream>>>(colv, E, deg, rank, cB);
  k_scan1<<<nTiles, 256, 0, stream>>>(deg, n, bat, x, od, dx, sd,
                                      fitsA ? P : nullptr, ts);
  k_scan2<<<1, 128, 0, stream>>>(ts, nTiles);

  // CSR fill (4B payload) + layer-1 scalar aggregation (+ P accumulation in Path A)
  k_edge<<<(E + 255) / 256, 256, 0, stream>>>(rowv, colv, rank, E, od, ts, dx, sd, gwi,
                                              fitsA ? P : nullptr);

  // fused rank-1 h1 + relu + layer-2 aggregation -> z (bufB)
  k_l2in<<<(n + 3) / 4, 256, 0, stream>>>(sd, od, ts, gwi, W1, b1, (float2*)bufB, n, E);

  // layer 2 GEMM (+bias+relu): bufB @ W2 -> bufA — broadcast-A, no LDS/barriers
  k_gemm2<<<(n + 127) / 128, 256, 0, stream>>>(bufB, W2, b2, bufA, n);

  if (!fitsA) {
    hipMemsetAsync(P, 0, (size_t)n * NGRAPH * 4, stream);
    k_pbuild<<<(E + n + 255) / 256, 256, 0, stream>>>(rowv, colv, E, od, dx, P, n);
  }

  // layer 3 + pool: partials = P^T * h2 per block, then parallel reduce
  k_pgemm<<<nPB, 256, 0, stream>>>(bufA, P, partials, n);
  k_reduce<<<dim3(32, 8), 256, 0, stream>>>(partials, pooled, nPB);

  // fused tail: mid GEMM + classifier
  k_mid<<<NGRAPH, HDIM, 0, stream>>>(pooled, bat, n, W3, b3, Wl, bl, out);
}

// Round 14
// 356.472 us; speedup vs baseline: 1.4487x; 1.4487x over previous
//
#include <hip/hip_runtime.h>

#define HDIM 128
#define NGRAPH 64
#define NCLASS 7
#define PG_NODES 192  // nodes per k_pgemm block (3 sub-chunks of 64)

// ---------------- count in-degree (+edge rank, 4 strided edges/thread) + W2 transpose ----------------

__global__ void k_countw(const int* __restrict__ col, int E, int* __restrict__ deg,
                         int* __restrict__ rank, const float* __restrict__ W,
                         float* __restrict__ WT, int cB) {
  int b = blockIdx.x;
  if (b < cB) {
    int tid = b * 256 + threadIdx.x;
    int stride = cB << 8;
#pragma unroll
    for (int k = 0; k < 4; k++) {
      int e = tid + k * stride;
      if (e < E) rank[e] = atomicAdd(&deg[col[e]], 1);
    }
  } else {
    int idx = (b - cB) * 256 + threadIdx.x;  // 0..16383
    int c = idx >> 7, k = idx & 127;
    WT[idx] = W[k * 128 + c];
  }
}

// exclusive scan of deg (tile-local) -> packed node metadata + self-term inits:
//   od[i] = { off_local | batch[i]<<24 , dinv_bits }
//   dx[i] = { dinv , x }                         (k_edge r-side)
//   sd[i] = { dinv^2 * x  (s self-init) , dinv } (k_l2in src-side; s accumulated into .x)
//   P[i][batch[i]] = dinv^2                      (self pooling coef; P pre-zeroed, Path A)
__global__ void k_scan1(const int* __restrict__ in, int n, const int* __restrict__ batch,
                        const float* __restrict__ x, int2* __restrict__ od,
                        float2* __restrict__ dx, float2* __restrict__ sd,
                        float* __restrict__ P, int* __restrict__ tileSums) {
  __shared__ int sh[256];
  int t = threadIdx.x;
  int base = blockIdx.x * 1024 + t * 4;
  int v[4], dg[4], sum = 0;
#pragma unroll
  for (int j = 0; j < 4; j++) {
    int idx = base + j;
    int d = (idx < n) ? in[idx] : 0;
    dg[j] = d;
    v[j] = sum; sum += d;
  }
  sh[t] = sum; __syncthreads();
  for (int o = 1; o < 256; o <<= 1) {
    int val = (t >= o) ? sh[t - o] : 0;
    __syncthreads();
    sh[t] += val;
    __syncthreads();
  }
  int excl = (t == 0) ? 0 : sh[t - 1];
  if (t == 255) tileSums[blockIdx.x] = sh[255];
#pragma unroll
  for (int j = 0; j < 4; j++) {
    int idx = base + j;
    if (idx < n) {
      int g = batch[idx];
      float xv = x[idx];
      float dinv = rsqrtf((float)(dg[j] + 1));  // +1 self-loop
      float dd = dinv * dinv;
      od[idx] = make_int2((excl + v[j]) | (g << 24), __float_as_int(dinv));
      dx[idx] = make_float2(dinv, xv);
      sd[idx] = make_float2(dd * xv, dinv);
      if (P) P[(size_t)idx * NGRAPH + g] = dd;
    }
  }
}

__global__ void k_scan2(int* __restrict__ tileSums, int numTiles) {
  __shared__ int sh[128];
  int t = threadIdx.x;
  sh[t] = (t < numTiles) ? tileSums[t] : 0;
  __syncthreads();
  for (int o = 1; o < 128; o <<= 1) {
    int val = (t >= o) ? sh[t - o] : 0;
    __syncthreads();
    sh[t] += val;
    __syncthreads();
  }
  if (t < numTiles) tileSums[t] = (t == 0) ? 0 : sh[t - 1];
}

// ---------------- edge pass: CSR fill (4B src payload) + layer-1 agg + P accumulation ----------------

__global__ void k_edge(const int* __restrict__ row, const int* __restrict__ col,
                       const int* __restrict__ rank, int E,
                       const int2* __restrict__ od, const int* __restrict__ ts,
                       const float2* __restrict__ dx,
                       float2* __restrict__ sd, int* __restrict__ gwi,
                       float* __restrict__ P) {
  int e = blockIdx.x * blockDim.x + threadIdx.x;
  if (e >= E) return;
  int r = row[e], c = col[e];
  int2 oc = od[c];
  float2 dr = dx[r];
  float w = dr.x * __int_as_float(oc.y);
  int g = ((unsigned)oc.x) >> 24;
  int pos = (oc.x & 0xFFFFFF) + ts[c >> 10] + rank[e];
  gwi[pos] = r;  // raw src index; g only needed for P (handled here in Path A)
  unsafeAtomicAdd(&sd[c].x, w * dr.y);
  if (P) unsafeAtomicAdd(&P[(size_t)r * NGRAPH + g], w);
}

// ---------------- P build fallback (Path B only) ----------------

__global__ void k_pbuild(const int* __restrict__ row, const int* __restrict__ col, int E,
                         const int2* __restrict__ od, const float2* __restrict__ dx,
                         float* __restrict__ P, int n) {
  int e = blockIdx.x * blockDim.x + threadIdx.x;
  if (e < E) {
    int r = row[e], c = col[e];
    int2 oc = od[c];
    float w = dx[r].x * __int_as_float(oc.y);
    unsafeAtomicAdd(&P[(size_t)r * NGRAPH + (((unsigned)oc.x) >> 24)], w);
  } else if (e - E < n) {
    int i = e - E;
    float d = dx[i].x;
    int g = ((unsigned)od[i].x) >> 24;
    unsafeAtomicAdd(&P[(size_t)i * NGRAPH + g], d * d);
  }
}

// ---------------- fused: h1 = relu(s*W1+b1) recomputed per edge + agg2 ----------------
// w recomputed = sd[src].y * dinv_dst (bit-identical to k_edge's product).

__global__ void __launch_bounds__(256) k_l2in(const float2* __restrict__ sd,
                                              const int2* __restrict__ od,
                                              const int* __restrict__ ts,
                                              const int* __restrict__ gwi,
                                              const float* __restrict__ W1,
                                              const float* __restrict__ b1,
                                              float2* __restrict__ z, int n, int E) {
  int node = blockIdx.x * 4 + (threadIdx.x >> 6);
  if (node >= n) return;
  int l = threadIdx.x & 63;
  float2 w1 = ((const float2*)W1)[l];
  float2 bv = ((const float2*)b1)[l];
  int2 on = od[node];
  float dstd = __int_as_float(on.y);
  float nself = dstd * dstd;
  float sv = sd[node].x;
  float2 acc;
  acc.x = nself * fmaxf(fmaf(sv, w1.x, bv.x), 0.f);
  acc.y = nself * fmaxf(fmaf(sv, w1.y, bv.y), 0.f);
  int e0 = (on.x & 0xFFFFFF) + ts[node >> 10];
  int e1 = (node + 1 < n) ? ((od[node + 1].x & 0xFFFFFF) + ts[(node + 1) >> 10]) : E;
  int e = e0;
  for (; e + 4 <= e1; e += 4) {
    int g0 = gwi[e], g1 = gwi[e + 1], g2 = gwi[e + 2], g3 = gwi[e + 3];
    float2 q0 = sd[g0], q1 = sd[g1];
    float2 q2 = sd[g2], q3 = sd[g3];
    float u0 = q0.y * dstd, u1 = q1.y * dstd, u2 = q2.y * dstd, u3 = q3.y * dstd;
    acc.x = fmaf(u0, fmaxf(fmaf(q0.x, w1.x, bv.x), 0.f), acc.x);
    acc.y = fmaf(u0, fmaxf(fmaf(q0.x, w1.y, bv.y), 0.f), acc.y);
    acc.x = fmaf(u1, fmaxf(fmaf(q1.x, w1.x, bv.x), 0.f), acc.x);
    acc.y = fmaf(u1, fmaxf(fmaf(q1.x, w1.y, bv.y), 0.f), acc.y);
    acc.x = fmaf(u2, fmaxf(fmaf(q2.x, w1.x, bv.x), 0.f), acc.x);
    acc.y = fmaf(u2, fmaxf(fmaf(q2.x, w1.y, bv.y), 0.f), acc.y);
    acc.x = fmaf(u3, fmaxf(fmaf(q3.x, w1.x, bv.x), 0.f), acc.x);
    acc.y = fmaf(u3, fmaxf(fmaf(q3.x, w1.y, bv.y), 0.f), acc.y);
  }
  for (; e < e1; e++) {
    float2 q = sd[gwi[e]];
    float w = q.y * dstd;
    acc.x = fmaf(w, fmaxf(fmaf(q.x, w1.x, bv.x), 0.f), acc.x);
    acc.y = fmaf(w, fmaxf(fmaf(q.x, w1.y, bv.y), 0.f), acc.y);
  }
  z[(size_t)node * 64 + l] = acc;
}

// ---------------- GEMM: (n x 128) @ (128 x 128) + bias + relu ----------------
// PERMANENTLY FROZEN R5 structure (76us, VGPR 68, no spill). Challenged 4x:
// R6 register prefetch -> scratch spill (1 GB HBM); R11 edge-walk fusion ->
// occupancy starvation (80 KB LDS); R13 broadcast-A no-LDS -> issue starvation
// (16 B/instr broadcast loads, VALUBusy 12%). This is the local optimum.

__global__ void __launch_bounds__(256, 3)
k_gemm(const float* __restrict__ A, const float* __restrict__ WT,
       const float* __restrict__ bias, float* __restrict__ out, int n) {
  __shared__ float4 As4[128 * 8];  // 16 KB
  __shared__ float4 Wt4[128 * 8];  // 16 KB
  const int t = threadIdx.x;
  const int tr = t >> 4;   // 0..15 row group (8 rows each)
  const int tc = t & 15;   // 0..15 col group (8 cols each)
  const int sa = tr & 7;
  const int sw = tc & 7;
  const int rowBase = blockIdx.x << 7;

  float acc[8][8] = {};

  for (int ch = 0; ch < 4; ch++) {
    const int kOff = ch << 5;
    __syncthreads();
    for (int l = t; l < 1024; l += 256) {
      int r = l >> 3, kq = l & 7;
      int grow = rowBase + r;
      float4 v = (grow < n) ? *(const float4*)&A[(size_t)grow * 128 + kOff + (kq << 2)]
                            : make_float4(0.f, 0.f, 0.f, 0.f);
      As4[(r << 3) + (kq ^ ((r >> 3) & 7))] = v;
    }
    for (int l = t; l < 1024; l += 256) {
      int c = l >> 3, kq = l & 7;
      float4 v = *(const float4*)&WT[(size_t)c * 128 + kOff + (kq << 2)];
      Wt4[(c << 3) + (kq ^ ((c >> 3) & 7))] = v;
    }
    __syncthreads();

    for (int kq = 0; kq < 8; kq++) {
      const int ka = kq ^ sa;
      const int kw = kq ^ sw;
      float4 a[8];
#pragma unroll
      for (int i = 0; i < 8; i++) a[i] = As4[(tr << 6) + (i << 3) + ka];
#pragma unroll
      for (int j = 0; j < 8; j++) {
        float4 w = Wt4[(tc << 6) + (j << 3) + kw];
#pragma unroll
        for (int i = 0; i < 8; i++) {
          float v = acc[i][j];
          v = fmaf(a[i].x, w.x, v);
          v = fmaf(a[i].y, w.y, v);
          v = fmaf(a[i].z, w.z, v);
          v = fmaf(a[i].w, w.w, v);
          acc[i][j] = v;
        }
      }
    }
  }

  const float4 b0 = *(const float4*)&bias[(tc << 3)];
  const float4 b1v = *(const float4*)&bias[(tc << 3) + 4];
#pragma unroll
  for (int i = 0; i < 8; i++) {
    int grow = rowBase + (tr << 3) + i;
    if (grow < n) {
      float4 o0, o1;
      o0.x = fmaxf(acc[i][0] + b0.x, 0.f);
      o0.y = fmaxf(acc[i][1] + b0.y, 0.f);
      o0.z = fmaxf(acc[i][2] + b0.z, 0.f);
      o0.w = fmaxf(acc[i][3] + b0.w, 0.f);
      o1.x = fmaxf(acc[i][4] + b1v.x, 0.f);
      o1.y = fmaxf(acc[i][5] + b1v.y, 0.f);
      o1.z = fmaxf(acc[i][6] + b1v.z, 0.f);
      o1.w = fmaxf(acc[i][7] + b1v.w, 0.f);
      *(float4*)&out[(size_t)grow * 128 + (tc << 3)] = o0;
      *(float4*)&out[(size_t)grow * 128 + (tc << 3) + 4] = o1;
    }
  }
}

// ---------------- layer 3 + pool: partials[b] = P_b^T * H_b ----------------

__global__ void __launch_bounds__(256) k_pgemm(const float* __restrict__ H,
                                               const float* __restrict__ P,
                                               float* __restrict__ partials, int n) {
  __shared__ float4 Hl4[64 * 32];  // [i][j-quad]
  __shared__ float4 Pl4[64 * 16];  // [i][g-quad]
  const int t = threadIdx.x;
  const int jl = t & 31;
  const int gq = (t >> 5) << 1;
  float4 acc[8];
#pragma unroll
  for (int i = 0; i < 8; i++) acc[i] = make_float4(0.f, 0.f, 0.f, 0.f);
  const int base0 = blockIdx.x * PG_NODES;

  for (int sub = 0; sub < PG_NODES / 64; sub++) {
    const int base = base0 + sub * 64;
    __syncthreads();
    for (int l = t; l < 2048; l += 256) {
      int i = l >> 5, q = l & 31;
      int node = base + i;
      Hl4[l] = (node < n) ? *(const float4*)&H[(size_t)node * 128 + (q << 2)]
                          : make_float4(0.f, 0.f, 0.f, 0.f);
    }
    for (int l = t; l < 1024; l += 256) {
      int i = l >> 4, q = l & 15;
      int node = base + i;
      Pl4[l] = (node < n) ? *(const float4*)&P[(size_t)node * NGRAPH + (q << 2)]
                          : make_float4(0.f, 0.f, 0.f, 0.f);
    }
    __syncthreads();

#define FMA4(A, PV) \
  A.x = fmaf(PV, hv.x, A.x); A.y = fmaf(PV, hv.y, A.y); \
  A.z = fmaf(PV, hv.z, A.z); A.w = fmaf(PV, hv.w, A.w);
#pragma unroll 4
    for (int i = 0; i < 64; i++) {
      float4 hv = Hl4[i * 32 + jl];
      float4 pa = Pl4[i * 16 + gq];
      float4 pb = Pl4[i * 16 + gq + 1];
      FMA4(acc[0], pa.x) FMA4(acc[1], pa.y) FMA4(acc[2], pa.z) FMA4(acc[3], pa.w)
      FMA4(acc[4], pb.x) FMA4(acc[5], pb.y) FMA4(acc[6], pb.z) FMA4(acc[7], pb.w)
    }
#undef FMA4
  }

  float* dst = &partials[(size_t)blockIdx.x * (NGRAPH * HDIM)];
  int gb = (t >> 5) << 3;
#pragma unroll
  for (int gi = 0; gi < 8; gi++)
    *(float4*)&dst[(gb + gi) * HDIM + (jl << 2)] = acc[gi];
}

// parallel partials reduce: grid (32, 8), block 256
__global__ void k_reduce(const float* __restrict__ partials, float* __restrict__ pooled,
                         int nparts) {
  int cell = blockIdx.x * 256 + threadIdx.x;
  int stride = gridDim.y;
  int p = blockIdx.y;
  float a0 = 0.f, a1 = 0.f, a2 = 0.f, a3 = 0.f;
  for (; p + 3 * stride < nparts; p += 4 * stride) {
    a0 += partials[(size_t)p * 8192 + cell];
    a1 += partials[(size_t)(p + stride) * 8192 + cell];
    a2 += partials[(size_t)(p + 2 * stride) * 8192 + cell];
    a3 += partials[(size_t)(p + 3 * stride) * 8192 + cell];
  }
  for (; p < nparts; p += stride) a0 += partials[(size_t)p * 8192 + cell];
  unsafeAtomicAdd(&pooled[cell], (a0 + a1) + (a2 + a3));
}

// fused tail: t1 = pooled/cnt @ W3 + b3 (in LDS), then out = t1 @ Wl + bl
__global__ void k_mid(const float* __restrict__ pooled, const int* __restrict__ batch, int n,
                      const float* __restrict__ W3, const float* __restrict__ b3,
                      const float* __restrict__ Wl, const float* __restrict__ bl,
                      float* __restrict__ out) {
  __shared__ float sh[HDIM];
  __shared__ float invSh;
  int g = blockIdx.x, j = threadIdx.x;
  if (j == 0) {
    int lo = 0, hi = n;
    while (lo < hi) { int m = (lo + hi) >> 1; if (batch[m] < g) lo = m + 1; else hi = m; }
    int a = lo;
    lo = 0; hi = n;
    while (lo < hi) { int m = (lo + hi) >> 1; if (batch[m] < g + 1) lo = m + 1; else hi = m; }
    invSh = 1.f / fmaxf((float)(lo - a), 1.f);
  }
  __syncthreads();
  float inv = invSh;
  float acc = 0.f;
  for (int k = 0; k < HDIM; k++) acc = fmaf(pooled[g * HDIM + k], W3[k * HDIM + j], acc);
  sh[j] = acc * inv + b3[j];
  __syncthreads();
  if (j < NCLASS) {
    float o = bl[j];
    for (int k = 0; k < HDIM; k++) o = fmaf(sh[k], Wl[k * NCLASS + j], o);
    out[g * NCLASS + j] = o;
  }
}

// ---------------- host ----------------

extern "C" void kernel_launch(void* const* d_in, const int* in_sizes, int n_in,
                              void* d_out, int out_size, void* d_ws, size_t ws_size,
                              hipStream_t stream) {
  const float* x   = (const float*)d_in[0];
  const int*   ei  = (const int*)d_in[1];
  const int*   bat = (const int*)d_in[2];
  const float* W1  = (const float*)d_in[3];
  const float* b1  = (const float*)d_in[4];
  const float* W2  = (const float*)d_in[5];
  const float* b2  = (const float*)d_in[6];
  const float* W3  = (const float*)d_in[7];
  const float* b3  = (const float*)d_in[8];
  const float* Wl  = (const float*)d_in[9];
  const float* bl  = (const float*)d_in[10];
  float* out = (float*)d_out;

  const int n = in_sizes[0];
  const int E = in_sizes[1] / 2;
  const int* rowv = ei;            // edge_index[0] : message source
  const int* colv = ei + E;        // edge_index[1] : aggregation destination

  char* w = (char*)d_ws;
  size_t o = 0;
  auto alloc = [&](size_t bytes) {
    size_t r = (o + 255) & ~(size_t)255;
    o = r + bytes;
    return r;
  };
  const int nPB = (n + PG_NODES - 1) / PG_NODES;

  // Path A layout: standalone P + partials; single upfront memset (deg, pooled, P).
  size_t o_deg  = alloc((size_t)n * 4);
  size_t o_pool = alloc((size_t)NGRAPH * HDIM * 4);
  size_t o_P    = alloc((size_t)n * NGRAPH * 4);  // 25.6 MB
  size_t zero_end = o;
  size_t o_ts   = alloc(256 * 4);
  size_t o_od   = alloc((size_t)n * 8);
  size_t o_dx   = alloc((size_t)n * 8);
  size_t o_sd   = alloc((size_t)n * 8);
  size_t o_rank = alloc((size_t)E * 4);
  size_t o_wt   = alloc((size_t)HDIM * HDIM * 4);
  size_t o_gw   = alloc((size_t)E * 4);
  size_t o_bufA = alloc((size_t)n * HDIM * 4);
  size_t o_bufB = alloc((size_t)n * HDIM * 4);
  size_t o_part = alloc((size_t)nPB * NGRAPH * HDIM * 4);  // ~17 MB
  const bool fitsA = (o <= ws_size);
  (void)n_in; (void)out_size;

  if (!fitsA) {
    // Path B: P + partials alias bufB (z dead after gemm); P built by k_pbuild.
    o = 0;
    o_deg  = alloc((size_t)n * 4);
    o_pool = alloc((size_t)NGRAPH * HDIM * 4);
    zero_end = o;
    o_ts   = alloc(256 * 4);
    o_od   = alloc((size_t)n * 8);
    o_dx   = alloc((size_t)n * 8);
    o_sd   = alloc((size_t)n * 8);
    o_rank = alloc((size_t)E * 4);
    o_wt   = alloc((size_t)HDIM * HDIM * 4);
    o_gw   = alloc((size_t)E * 4);
    o_bufA = alloc((size_t)n * HDIM * 4);
    o_bufB = alloc((size_t)n * HDIM * 4);
    o_P    = o_bufB;
    o_part = o_bufB + (size_t)n * NGRAPH * 4;
  }

  int*    deg      = (int*)(w + o_deg);
  float*  pooled   = (float*)(w + o_pool);
  int*    ts       = (int*)(w + o_ts);
  int2*   od       = (int2*)(w + o_od);
  float2* dx       = (float2*)(w + o_dx);
  float2* sd       = (float2*)(w + o_sd);
  int*    rank     = (int*)(w + o_rank);
  float*  W2T      = (float*)(w + o_wt);
  int*    gwi      = (int*)(w + o_gw);
  float*  bufA     = (float*)(w + o_bufA);   // h2 (gemm out)
  float*  bufB     = (float*)(w + o_bufB);   // z (gemm in)
  float*  P        = (float*)(w + o_P);
  float*  partials = (float*)(w + o_part);

  hipMemsetAsync(w + o_deg, 0, zero_end - o_deg, stream);

  const int nTiles = (n + 1023) / 1024;
  const int cB = (E + 1023) / 1024;  // 4 strided edges per thread
  k_countw<<<cB + 64, 256, 0, stream>>>(colv, E, deg, rank, W2, W2T, cB);
  k_scan1<<<nTiles, 256, 0, stream>>>(deg, n, bat, x, od, dx, sd,
                                      fitsA ? P : nullptr, ts);
  k_scan2<<<1, 128, 0, stream>>>(ts, nTiles);

  // CSR fill (4B payload) + layer-1 scalar aggregation (+ P accumulation in Path A)
  k_edge<<<(E + 255) / 256, 256, 0, stream>>>(rowv, colv, rank, E, od, ts, dx, sd, gwi,
                                              fitsA ? P : nullptr);

  // fused rank-1 h1 + relu + layer-2 aggregation -> z (bufB)
  k_l2in<<<(n + 3) / 4, 256, 0, stream>>>(sd, od, ts, gwi, W1, b1, (float2*)bufB, n, E);

  // layer 2 GEMM (+bias+relu): bufB @ W2 -> bufA (frozen LDS kernel)
  k_gemm<<<(n + 127) / 128, 256, 0, stream>>>(bufB, W2T, b2, bufA, n);

  if (!fitsA) {
    hipMemsetAsync(P, 0, (size_t)n * NGRAPH * 4, stream);
    k_pbuild<<<(E + n + 255) / 256, 256, 0, stream>>>(rowv, colv, E, od, dx, P, n);
  }

  // layer 3 + pool: partials = P^T * h2 per block, then parallel reduce
  k_pgemm<<<nPB, 256, 0, stream>>>(bufA, P, partials, n);
  k_reduce<<<dim3(32, 8), 256, 0, stream>>>(partials, pooled, nPB);

  // fused tail: mid GEMM + classifier
  k_mid<<<NGRAPH, HDIM, 0, stream>>>(pooled, bat, n, W3, b3, Wl, bl, out);
}